// Round 6
// baseline (336.744 us; speedup 1.0000x reference)
//
#include <hip/hip_runtime.h>
#include <math.h>

// DiffDispatchLP: batched (256x) PDHG, 400 iters, one WG (8 waves) per item.
// Consumer-indexed record packing: phase B scatters dual combos into 4-dword
// records laid out per consuming column (phase A = 1-2 ds_read_b128/thread);
// x_bar packed as {c,d,yc,yd} records + scalar soc/ymd arrays so phase-B row
// tasks read b128/b64. All records stride-4, guard records absorb boundaries.

#define NITER 400
#define PITER 10

// dword offsets in sy
#define CDB_C 0      // {bC, eq, um, up} per c-column t (96 rec)
#define CDB_D 384    // same for d
#define YBA0  768    // {k1,k2,k3,m0} per yc-col, t 0..97 (98 rec)
#define YBA1  1160   // yd
#define YBB0T 1556   // {m1,bY,s0,s1} per yc-col, records t -1..95 (t0 here)
#define YBB1T 1944   // yd
#define SBT   2332   // {bS,e0,e1,pad} per soc-col, t -1..95 (t0 here)
#define XBA0  2720   // {c,d,yc,yd} x_bar records, t -1..96 (t0 here)
#define XS0   3109   // soc x_bar scalar, t -1..96 (t0 here)
#define XC0   3206   // c x_bar copy, t 0..95 (for TC reduce)
#define YMD0T 3303   // yc x_bar scalar, t -1..97 (t0 here)
#define YMD1T 3402   // yd
#define TCS   3500
#define REDO  3504
#define NYTOT 3512

__global__ __launch_bounds__(512, 1)
void lp_solve_kernel(const float* __restrict__ price, float* __restrict__ out) {
  __shared__ __align__(16) float sy[NYTOT];

  const int tid = threadIdx.x, lane = tid & 63, wid = tid >> 6, bi = blockIdx.x;
  const double ETA_D = sqrt(0.91);
  const float cET = (float)(-(ETA_D * 0.25));  // -ETA*DT
  const float cDE = (float)(0.25 / ETA_D);     // DT/ETA

  // ================= phase A per-thread constants =================
  const bool colAct = (tid < 480);
  const int col = colAct ? tid : 479;
  const int vty = col / 96;            // 0 c, 1 d, 2 yc, 3 yd, 4 soc
  const int t = col - 96 * vty;
  const int v01 = vty & 1;
  // cd body (wid 0..2)
  const int aCD = (v01 ? CDB_D : CDB_C) + 4 * t;
  const float ce = v01 ? cDE : cET;
  const float ctc = v01 ? 0.f : 0.25f;
  // y body (wid 3..5)
  const int yv = (vty >= 2) ? (vty - 2) : 0;
  const int aYA = (yv ? YBA1 : YBA0) + 4 * t;
  const int aYB = (yv ? YBB1T : YBB0T) + 4 * t;
  // soc body (wid 6..7)
  const int aSB4 = SBT + 4 * t;
  const float ce1 = (t <= 94) ? -1.f : 1.f;
  // x_bar write slots
  int wX, wX2; bool hasW2;
  if (vty == 0)      { wX = XBA0 + 4 * t;     wX2 = XC0 + t;   hasW2 = true; }
  else if (vty == 1) { wX = XBA0 + 4 * t + 1; wX2 = 0;         hasW2 = false; }
  else if (vty == 2) { wX = XBA0 + 4 * t + 2; wX2 = YMD0T + t; hasW2 = true; }
  else if (vty == 3) { wX = XBA0 + 4 * t + 3; wX2 = YMD1T + t; hasW2 = true; }
  else               { wX = XS0 + t;          wX2 = 0;         hasW2 = false; }

  // ================= phase B per-thread constants =================
  // BOX: w0 t=lane; w1 lanes<32 t=64+lane
  const bool bAct = (wid == 0) || (wid == 1 && lane < 32);
  const int tb = (wid == 0) ? lane : (64 + (lane & 31));
  // SW: w1 lanes>=32 t=0..31; w6 lanes<63 t=32..94
  const bool sRun = (wid == 1) || (wid == 6);
  const bool sAct = (wid == 1) ? (lane >= 32) : (wid == 6 && lane < 63);
  const int st = (wid == 1) ? ((lane >= 32) ? lane - 32 : 0)
                            : (32 + ((lane < 63) ? lane : 62));
  // MD: w2 i=lane, w3 i=64+lane, w4 i=128+lane (i<190)
  const bool mdRun = (wid >= 2) && (wid <= 4);
  const int mi0 = ((wid - 2) << 6) + lane;
  const bool mdAct = mdRun && (mi0 < 190);
  const int mi = mdAct ? mi0 : 189;
  const int mv = (mi >= 95) ? 1 : 0;
  const int mt = mi - 95 * mv;
  const int ymdb = (mv ? YMD1T : YMD0T) + mt;
  const int ya = (mv ? YBA1 : YBA0) + 4 * mt;
  const int yb = (mv ? YBB1T : YBB0T) + 4 * mt;
  const float cv2 = (mt <= 93) ? 1.f : 0.f;
  const float cv3 = (mt <= 92) ? 1.f : 0.f;
  // RAMP: w5 rt=1..64; w6 lanes<31 rt=65..95
  const bool rRun = (wid == 5) || (wid == 6);
  const bool rAct = (wid == 5) || (wid == 6 && lane < 31);
  const int rt = (wid == 5) ? (1 + lane) : (65 + ((lane < 31) ? lane : 30));
  // EQ: w5 r=0..63; w7 lanes<33 r=64..96
  const bool eqRun = (wid == 5) || (wid == 7);
  const bool eqAct = (wid == 5) || (wid == 7 && lane < 33);
  const int er = (wid == 5) ? lane : (64 + ((lane < 33) ? lane : 32));
  const bool erLe95 = eqAct && (er <= 95);
  const float cEb = (er == 96) ? -1.f : 1.f;

  // ================= state =================
  float xA = 0.f, qA = 0.f;
  float yb0=0,yb1=0,yb2=0,yb3=0,yb4=0,yb5=0,yb6=0,yb7=0,yb8=0,yb9=0,yb10=0,yb11=0,yb12=0;
  float ym1=0, ym2=0, ym3=0, yr0=0, yr1=0, yr2=0, yr3=0, ysw0=0, ysw1=0, yeq=0, ytc=0;
  float tauv = 0.f, sigv = 0.f;

  auto gatherA = [&]() -> float {
    if (wid < 3) {
      float4 cb = *(const float4*)&sy[aCD];   // {bC, eq, um, up}
      float tc = sy[TCS];
      return cb.x + ce * cb.y + cb.z - cb.w + ctc * tc;
    } else if (wid < 6) {
      float4 a = *(const float4*)&sy[aYA];    // {k1,k2,k3,m0}
      float4 b = *(const float4*)&sy[aYB];    // {m1,bY,s0,s1}
      return b.y + b.z + b.w + (a.w - b.x) - (a.x + a.y + a.z);
    } else {
      float4 s4 = *(const float4*)&sy[aSB4];  // {bS,e0,e1,pad}
      return s4.x + s4.y + ce1 * s4.z;
    }
  };

  auto writeX = [&](float v) {
    if (colAct) {
      sy[wX] = v;
      if (hasW2) sy[wX2] = v;
    }
  };

  auto phaseB = [&](bool power) {
    const float sig = sigv;
    if (wid <= 1) {  // BOX: 13 rows at tb -> 5 combos
      float4 x4 = *(const float4*)&sy[XBA0 + 4 * tb];
      float c_ = x4.x, d_ = x4.y, yc_ = x4.z, yd_ = x4.w;
      float s_ = sy[XS0 + tb];
      float v0,v1,v2,v3,v4,v5,v6,v7,v8,v9,v10,v11,v12;
      if (power) {
        v0=c_; v1=d_; v2=-c_; v3=-d_; v4=-yc_; v5=yc_; v6=-yd_; v7=yd_;
        v8=-s_; v9=s_; v10=yc_+yd_; v11=c_-195.f*yc_; v12=d_-195.f*yd_;
      } else {
        yb0  = fmaxf(yb0  + sig*(c_  - 195.f), 0.f);      v0 = yb0;
        yb1  = fmaxf(yb1  + sig*(d_  - 195.f), 0.f);      v1 = yb1;
        yb2  = fmaxf(yb2  - sig*c_,            0.f);      v2 = yb2;
        yb3  = fmaxf(yb3  - sig*d_,            0.f);      v3 = yb3;
        yb4  = fmaxf(yb4  - sig*yc_,           0.f);      v4 = yb4;
        yb5  = fmaxf(yb5  + sig*(yc_ - 1.f),   0.f);      v5 = yb5;
        yb6  = fmaxf(yb6  - sig*yd_,           0.f);      v6 = yb6;
        yb7  = fmaxf(yb7  + sig*(yd_ - 1.f),   0.f);      v7 = yb7;
        yb8  = fmaxf(yb8  - sig*s_,            0.f);      v8 = yb8;
        yb9  = fmaxf(yb9  + sig*(s_ - 800.f),  0.f);      v9 = yb9;
        yb10 = fmaxf(yb10 + sig*(yc_ + yd_ - 1.f), 0.f);  v10 = yb10;
        yb11 = fmaxf(yb11 + sig*(c_ - 195.f*yc_), 0.f);   v11 = yb11;
        yb12 = fmaxf(yb12 + sig*(d_ - 195.f*yd_), 0.f);   v12 = yb12;
      }
      if (bAct) {
        sy[CDB_C + 4 * tb]     = v0 - v2 + v11;                 // bC
        sy[CDB_D + 4 * tb]     = v1 - v3 + v12;                 // bD
        sy[YBB0T + 4 * tb + 1] = -v4 + v5 + v10 - 195.f * v11;  // bYC
        sy[YBB1T + 4 * tb + 1] = -v6 + v7 + v10 - 195.f * v12;  // bYD
        sy[SBT   + 4 * tb]     = -v8 + v9;                      // bS
      }
    }
    if (sRun) {  // SWITCH: 2 rows at st -> consumer-slot scatter
      float2 y0 = *(const float2*)&sy[XBA0 + 4 * st + 2];   // {yc,yd} at st
      float2 y1 = *(const float2*)&sy[XBA0 + 4 * st + 6];   // at st+1
      float p0, p1;
      if (power) { p0 = y0.x + y1.y; p1 = y0.y + y1.x; }
      else {
        ysw0 = fmaxf(ysw0 + sig * (y0.x + y1.y - 1.f), 0.f); p0 = ysw0;
        ysw1 = fmaxf(ysw1 + sig * (y0.y + y1.x - 1.f), 0.f); p1 = ysw1;
      }
      if (sAct) {
        sy[YBB0T + 4 * st + 2] = p0;   // s0 of (yc,st)
        sy[YBB1T + 4 * st + 7] = p0;   // s1 of (yd,st+1)
        sy[YBB1T + 4 * st + 2] = p1;   // s0 of (yd,st)
        sy[YBB0T + 4 * st + 7] = p1;   // s1 of (yc,st+1)
      }
    }
    if (mdRun) {  // MIN-DURATION: 3 rows + own-sum at (mv,mt)
      float mp = sy[ymdb - 1];
      float mc = sy[ymdb], m1v = sy[ymdb + 1];
      float m2v = sy[ymdb + 2], m3v = sy[ymdb + 3];
      float base = mc - mp;
      float d1 = base - m1v, d2 = base - m2v, d3 = base - m3v;
      float o1, o2, o3;
      if (power) { o1 = d1; o2 = d2; o3 = d3; }
      else {
        ym1 = fmaxf(ym1 + sig * d1, 0.f); o1 = ym1;
        ym2 = fmaxf(ym2 + sig * d2, 0.f); o2 = ym2;
        ym3 = fmaxf(ym3 + sig * d3, 0.f); o3 = ym3;
      }
      if (mdAct) {
        float ms = o1 + cv2 * o2 + cv3 * o3;
        sy[ya + 4]  = o1;   // k1 of col mt+1
        sy[ya + 9]  = o2;   // k2 of col mt+2
        sy[ya + 14] = o3;   // k3 of col mt+3
        sy[ya + 3]  = ms;   // m0 of col mt
        sy[yb - 4]  = ms;   // m1 of col mt-1
      }
    }
    if (rRun) {  // RAMP: 4 rows -> 2 combos, 2 consumer slots each
      float2 xm = *(const float2*)&sy[XBA0 + 4 * rt - 4];   // {c,d} at rt-1
      float2 x0 = *(const float2*)&sy[XBA0 + 4 * rt];
      float u0, u1, u2, u3;
      if (power) { u0 = x0.x - xm.x; u1 = xm.x - x0.x; u2 = x0.y - xm.y; u3 = xm.y - x0.y; }
      else {
        yr0 = fmaxf(yr0 + sig * (x0.x - xm.x - 65.f), 0.f); u0 = yr0;
        yr1 = fmaxf(yr1 + sig * (xm.x - x0.x - 65.f), 0.f); u1 = yr1;
        yr2 = fmaxf(yr2 + sig * (x0.y - xm.y - 65.f), 0.f); u2 = yr2;
        yr3 = fmaxf(yr3 + sig * (xm.y - x0.y - 65.f), 0.f); u3 = yr3;
      }
      if (rAct) {
        float uc = u0 - u1, ud = u2 - u3;
        sy[CDB_C + 4 * rt + 2] = uc;   // um of col rt
        sy[CDB_C + 4 * rt - 1] = uc;   // up of col rt-1
        sy[CDB_D + 4 * rt + 2] = ud;
        sy[CDB_D + 4 * rt - 1] = ud;
      }
    }
    if (eqRun) {  // EQUALITY row er (free dual)
      float2 cd2 = *(const float2*)&sy[XBA0 + 4 * er];      // {c,d} (guard at 96)
      float ep = sy[XS0 + er - 1], ecur = sy[XS0 + er];
      float dot = ecur - cEb * ep + cET * cd2.x + cDE * cd2.y;
      float ev;
      if (power) ev = dot;
      else { yeq += sig * dot; ev = yeq; }
      if (erLe95) {
        sy[CDB_C + 4 * er + 1] = ev;   // eq of col c_er
        sy[CDB_D + 4 * er + 1] = ev;   // eq of col d_er
        sy[SBT   + 4 * er + 1] = ev;   // e0 of col s_er
      }
      if (eqAct) sy[SBT + 4 * er - 2] = ev;   // e1 of col s_{er-1} (guard at er=0)
    }
    if (wid == 7) {  // TOTAL-CHARGE: 0.25 * sum(c_bar) <= 1200
      float ssum = sy[XC0 + lane] + ((lane < 32) ? sy[XC0 + 64 + lane] : 0.f);
#pragma unroll
      for (int m = 32; m >= 1; m >>= 1) ssum += __shfl_xor(ssum, m, 64);
      if (lane == 0) {
        float wv;
        if (power) wv = 0.25f * ssum;
        else { ytc = fmaxf(ytc + sig * (0.25f * ssum - 1200.f), 0.f); wv = ytc; }
        sy[TCS] = wv;
      }
    }
  };

  // ================= power iteration: ||K||_2 =================
  for (int i = tid; i < NYTOT; i += 512) sy[i] = 0.f;
  __syncthreads();
  writeX(1.f);
  __syncthreads();

  float lam2 = 1.f;
  for (int pit = 0; pit < PITER; ++pit) {
    phaseB(true);                      // sy = combined(K v)
    __syncthreads();
    float gA = gatherA();              // (K^T K v) per column
    if (!colAct) gA = 0.f;
    float part = gA * gA;
#pragma unroll
    for (int m = 32; m >= 1; m >>= 1) part += __shfl_xor(part, m, 64);
    if (lane == 0) sy[REDO + wid] = part;
    __syncthreads();
    lam2 = sqrtf(sy[REDO] + sy[REDO+1] + sy[REDO+2] + sy[REDO+3]
               + sy[REDO+4] + sy[REDO+5] + sy[REDO+6] + sy[REDO+7]);
    float inv = 1.f / lam2;
    writeX(gA * inv);
    __syncthreads();
  }
  tauv = (float)(0.9 / sqrt((double)lam2));
  sigv = tauv;

  // ================= PDHG =================
  __syncthreads();
  for (int i = tid; i < NYTOT; i += 512) sy[i] = 0.f;
  if (tid < 96)       qA =  0.25f * price[bi * 96 + tid];
  else if (tid < 192) qA = -0.25f * price[bi * 96 + (tid - 96)];
  __syncthreads();

#pragma unroll 1
  for (int it = 0; it < NITER; ++it) {
    float gA = gatherA();
    if (colAct) {
      float xa = xA - tauv * (qA + gA);
      float xbv = 2.f * xa - xA;
      xA = xa;
      sy[wX] = xbv;
      if (hasW2) sy[wX2] = xbv;
    }
    __syncthreads();
    phaseB(false);
    __syncthreads();
  }

  // output: c then d, each (256,96)
  if (tid < 96)       out[bi * 96 + tid] = xA;
  else if (tid < 192) out[24576 + bi * 96 + (tid - 96)] = xA;
}

extern "C" void kernel_launch(void* const* d_in, const int* in_sizes, int n_in,
                              void* d_out, int out_size, void* d_ws, size_t ws_size,
                              hipStream_t stream) {
  const float* price = (const float*)d_in[0];
  float* outp = (float*)d_out;
  hipLaunchKernelGGL(lp_solve_kernel, dim3(256), dim3(512), 0, stream, price, outp);
}